// Round 5
// baseline (1045.892 us; speedup 1.0000x reference)
//
#include <hip/hip_runtime.h>
#include <hip/hip_bf16.h>

typedef __attribute__((ext_vector_type(8))) short short8;
typedef __attribute__((ext_vector_type(4))) float floatx4;
typedef __hip_bfloat16 bf16;

__device__ __forceinline__ float b2f(bf16 v) { return __bfloat162float(v); }
__device__ __forceinline__ bf16 f2b(float v) { return __float2bfloat16(v); }
__device__ __forceinline__ short f2s(float v) {
  union { bf16 b; short s; } u; u.b = f2b(v); return u.s;
}

// flag: 1 = d_in tensors are f32 (reference dtype), 0 = bf16
__device__ __forceinline__ float ldin(const void* p, size_t i, int f) {
  return f ? ((const float*)p)[i] : b2f(((const bf16*)p)[i]);
}
template<bool F>
__device__ __forceinline__ float ldinT(const void* p, size_t i) {
  if constexpr (F) return ((const float*)p)[i];
  else return b2f(((const bf16*)p)[i]);
}
// store to d_out in flag dtype
__device__ __forceinline__ void stout(void* p, size_t i, float v, int f32) {
  if (f32) ((float*)p)[i] = v;
  else ((bf16*)p)[i] = f2b(v);
}
// 8 consecutive K-elements -> bf16x8 MFMA fragment
template<bool F>
__device__ __forceinline__ short8 ldfrag(const void* base, size_t off) {
  if constexpr (F) {
    const float* p = (const float*)base + off;
    const floatx4 lo = *(const floatx4*)p;
    const floatx4 hi = *(const floatx4*)(p + 4);
    short8 r;
    r[0] = f2s(lo[0]); r[1] = f2s(lo[1]); r[2] = f2s(lo[2]); r[3] = f2s(lo[3]);
    r[4] = f2s(hi[0]); r[5] = f2s(hi[1]); r[6] = f2s(hi[2]); r[7] = f2s(hi[3]);
    return r;
  } else {
    return *(const short8*)((const bf16*)base + off);
  }
}

__device__ __forceinline__ float silu(float v) {
  const float e = expf(-fabsf(v));
  const float sig = (v >= 0.f) ? 1.f / (1.f + e) : e / (1.f + e);
  return v * sig;
}
__device__ __forceinline__ float softplus(float v) {
  return fmaxf(v, 0.f) + log1pf(expf(-fabsf(v)));
}

// dtype probe: img_ln_g is all-ones. bf16 -> u16[0]==0x3F80; f32 -> 0x0000.
__global__ void detect_kernel(const unsigned short* __restrict__ probe,
                              int* __restrict__ flag) {
  if (threadIdx.x == 0 && blockIdx.x == 0)
    *flag = (probe[0] == (unsigned short)0x3F80) ? 0 : 1;
}

// ---------------------------------------------------------------------------
// GEMM: C[M,N] = epi(X[M,K] @ W[N,K]^T); epilogues:
//   act=0: +bias(if bias)  act=1: relu(+bias)
//   act=2: silu(v*scale4[n*4+3]+bias[n])  act=3: silu(v)
// Per-wave 32x32 = 2x2 mfma_f32_16x16x32_bf16; block = 4 waves = 64x64 tile.
// A: X[m16+(lane&15)][k0+(lane>>4)*8+j]; B: W[n16+(lane&15)][k0+(lane>>4)*8+j]
// D: C[m16+(lane>>4)*4+r][n16+(lane&15)]   (m89/m120-verified mappings)
// ---------------------------------------------------------------------------
template<bool XF, bool WF>
__device__ __forceinline__ void gemm_body(
    const void* __restrict__ X, int lda,
    const void* __restrict__ W, int ldw,
    const void* __restrict__ bias, const void* __restrict__ scale4,
    bf16* __restrict__ C, int ldc,
    int M, int N, int K, int act,
    int m_base, int n_base, int lane)
{
  const int lr = lane & 15;
  const int kq = (lane >> 4) * 8;

  const int ma0 = min(m_base + lr, M - 1);
  const int ma1 = min(m_base + 16 + lr, M - 1);
  const int nb0 = min(n_base + lr, N - 1);
  const int nb1 = min(n_base + 16 + lr, N - 1);

  const size_t ox0 = (size_t)ma0 * lda + kq;
  const size_t ox1 = (size_t)ma1 * lda + kq;
  const size_t ow0 = (size_t)nb0 * ldw + kq;
  const size_t ow1 = (size_t)nb1 * ldw + kq;

  floatx4 acc00 = {0.f, 0.f, 0.f, 0.f};
  floatx4 acc01 = acc00, acc10 = acc00, acc11 = acc00;

  for (int k0 = 0; k0 < K; k0 += 32) {
    short8 a0 = ldfrag<XF>(X, ox0 + k0);
    short8 a1 = ldfrag<XF>(X, ox1 + k0);
    short8 b0 = ldfrag<WF>(W, ow0 + k0);
    short8 b1 = ldfrag<WF>(W, ow1 + k0);
    acc00 = __builtin_amdgcn_mfma_f32_16x16x32_bf16(a0, b0, acc00, 0, 0, 0);
    acc01 = __builtin_amdgcn_mfma_f32_16x16x32_bf16(a0, b1, acc01, 0, 0, 0);
    acc10 = __builtin_amdgcn_mfma_f32_16x16x32_bf16(a1, b0, acc10, 0, 0, 0);
    acc11 = __builtin_amdgcn_mfma_f32_16x16x32_bf16(a1, b1, acc11, 0, 0, 0);
  }

  const int colx = lane & 15;
  const int rq = (lane >> 4) * 4;
  floatx4 accs[2][2] = {{acc00, acc01}, {acc10, acc11}};
#pragma unroll
  for (int im = 0; im < 2; ++im) {
#pragma unroll
    for (int jn = 0; jn < 2; ++jn) {
      const int n = n_base + jn * 16 + colx;
      if (n >= N) continue;
      const float bv = bias ? ldinT<WF>(bias, n) : 0.f;
      const float sv = (act == 2) ? ldinT<WF>(scale4, (size_t)n * 4 + 3) : 1.f;
#pragma unroll
      for (int r = 0; r < 4; ++r) {
        const int m = m_base + im * 16 + rq + r;
        if (m >= M) continue;
        float v = accs[im][jn][r];
        if (act == 2) v = silu(v * sv + bv);
        else if (act == 3) v = silu(v);
        else {
          v += bv;
          if (act == 1) v = fmaxf(v, 0.f);
        }
        C[(size_t)m * ldc + n] = f2b(v);
      }
    }
  }
}

__global__ __launch_bounds__(256) void gemm_mfma(
    const void* __restrict__ X, size_t xoff, int lda,
    const void* __restrict__ W, size_t woff, int ldw,
    const void* __restrict__ bias, size_t boff,
    const void* __restrict__ scale4, size_t soff,
    bf16* __restrict__ C, int ldc,
    int M, int N, int K, int act,
    const int* __restrict__ flagp, int x_is_input)
{
  const int lane = threadIdx.x & 63;
  const int wave = threadIdx.x >> 6;
  const int m_base = blockIdx.y * 64 + (wave >> 1) * 32;
  const int n_base = blockIdx.x * 64 + (wave & 1) * 32;
  const int f = *flagp;
  if (f) {
    const float* Wf = (const float*)W + woff;
    const float* bp = bias ? (const float*)bias + boff : nullptr;
    const float* sp = scale4 ? (const float*)scale4 + soff : nullptr;
    if (x_is_input)
      gemm_body<true, true>((const float*)X + xoff, lda, Wf, ldw, bp, sp,
                            C, ldc, M, N, K, act, m_base, n_base, lane);
    else
      gemm_body<false, true>((const bf16*)X + xoff, lda, Wf, ldw, bp, sp,
                             C, ldc, M, N, K, act, m_base, n_base, lane);
  } else {
    const bf16* Wb = (const bf16*)W + woff;
    const bf16* bp = bias ? (const bf16*)bias + boff : nullptr;
    const bf16* sp = scale4 ? (const bf16*)scale4 + soff : nullptr;
    gemm_body<false, false>((const bf16*)X + xoff, lda, Wb, ldw, bp, sp,
                            C, ldc, M, N, K, act, m_base, n_base, lane);
  }
}

// ---------------------------------------------------------------------------
__device__ __forceinline__ void block_reduce2(float& a, float& b) {
#pragma unroll
  for (int off = 32; off > 0; off >>= 1) {
    a += __shfl_down(a, off, 64);
    b += __shfl_down(b, off, 64);
  }
  __shared__ float sa[4], sb[4];
  const int lane = threadIdx.x & 63;
  const int wv = threadIdx.x >> 6;
  if (lane == 0) { sa[wv] = a; sb[wv] = b; }
  __syncthreads();
  a = sa[0] + sa[1] + sa[2] + sa[3];
  b = sb[0] + sb[1] + sb[2] + sb[3];
}

// LN over rows. out_mode=0: bf16 ws buffer; out_mode=1: d_out in flag dtype.
__global__ __launch_bounds__(256) void ln_kernel(
    const bf16* __restrict__ in, int in_ld,
    void* __restrict__ out, size_t out_eoff, int out_ld, int out_mode,
    const void* __restrict__ g, size_t goff,
    const void* __restrict__ b, size_t boff, int N,
    const int* __restrict__ flagp)
{
  __shared__ float vals[1024];
  const int f = *flagp;
  const int row = blockIdx.x;
  const bf16* ip = in + (size_t)row * in_ld;
  float s = 0.f, ss = 0.f;
  for (int j = threadIdx.x; j < N; j += 256) {
    float v = b2f(ip[j]);
    vals[j] = v; s += v; ss += v * v;
  }
  block_reduce2(s, ss);
  const float mean = s / N;
  const float inv = rsqrtf(fmaxf(ss / N - mean * mean, 0.f) + 1e-5f);
  const int of32 = out_mode ? f : 0;
  for (int j = threadIdx.x; j < N; j += 256) {
    const float v = (vals[j] - mean) * inv * ldin(g, goff + j, f) +
                    ldin(b, boff + j, f);
    stout(out, out_eoff + (size_t)row * out_ld + j, v, of32);
  }
}

// x = LN(mo + x_res) -> bf16 ws (in-place safe: reads precede barrier)
__global__ __launch_bounds__(256) void addln_kernel(
    const bf16* __restrict__ mo, const bf16* __restrict__ xres,
    bf16* __restrict__ out,
    const void* __restrict__ g, size_t goff,
    const void* __restrict__ b, size_t boff,
    const int* __restrict__ flagp)
{
  __shared__ float vals[1024];
  const int f = *flagp;
  const int row = blockIdx.x;
  float s = 0.f, ss = 0.f;
  for (int j = threadIdx.x; j < 1024; j += 256) {
    float v = b2f(mo[(size_t)row * 1024 + j]) + b2f(xres[(size_t)row * 1024 + j]);
    vals[j] = v; s += v; ss += v * v;
  }
  block_reduce2(s, ss);
  const float mean = s / 1024.f;
  const float inv = rsqrtf(fmaxf(ss / 1024.f - mean * mean, 0.f) + 1e-5f);
  for (int j = threadIdx.x; j < 1024; j += 256)
    out[(size_t)row * 1024 + j] =
        f2b((vals[j] - mean) * inv * ldin(g, goff + j, f) +
            ldin(b, boff + j, f));
}

// logits = h2 @ w3^T + b3 (N=2,K=256); softmax -> gate_f (ws) + d_out
__global__ __launch_bounds__(256) void gate3_kernel(
    const bf16* __restrict__ h2, const void* __restrict__ w3,
    const void* __restrict__ b3, float* __restrict__ gate_f,
    void* __restrict__ gate_out, size_t gout_eoff,
    const int* __restrict__ flagp)
{
  const int f = *flagp;
  const int row = blockIdx.x;
  const int t = threadIdx.x;
  const float h = b2f(h2[(size_t)row * 256 + t]);
  float p0 = h * ldin(w3, t, f);
  float p1 = h * ldin(w3, 256 + t, f);
  block_reduce2(p0, p1);
  if (t == 0) {
    const float l0 = p0 + ldin(b3, 0, f);
    const float l1 = p1 + ldin(b3, 1, f);
    const float mx = fmaxf(l0, l1);
    const float e0 = expf(l0 - mx), e1 = expf(l1 - mx);
    const float g0 = e0 / (e0 + e1), g1 = e1 / (e0 + e1);
    gate_f[row * 2] = g0;
    gate_f[row * 2 + 1] = g1;
    stout(gate_out, gout_eoff + (size_t)row * 2 + 0, g0, f);
    stout(gate_out, gout_eoff + (size_t)row * 2 + 1, g1, f);
  }
}

// x[b,0:512]=g0*cat[b,0:512]; x[b,512:1024]=g1*cat[b,512:1024]  (chunk-local)
__global__ __launch_bounds__(256) void combine_kernel(
    const bf16* __restrict__ cat, const float* __restrict__ gate_f,
    bf16* __restrict__ x)
{
  const int t = blockIdx.x * 256 + threadIdx.x;
  const int bidx = t >> 10, j = t & 1023;
  x[t] = f2b(gate_f[bidx * 2 + (j >> 9)] * b2f(cat[t]));
}

// In-place over du: u = (softplus(du+dtb)*xc*(Bc.Cc) + xc*Dp) * zsil
__global__ __launch_bounds__(256) void mamba_y_kernel(
    bf16* __restrict__ du, const void* __restrict__ dtb, size_t dtboff,
    const bf16* __restrict__ xc, const bf16* __restrict__ zsil,
    const bf16* __restrict__ dbc, const void* __restrict__ Dp, size_t dpoff,
    const int* __restrict__ flagp)
{
  const int f = *flagp;
  const int row = blockIdx.x;
  float bc = 0.f;
#pragma unroll
  for (int s2 = 0; s2 < 16; ++s2)
    bc += b2f(dbc[row * 96 + 64 + s2]) * b2f(dbc[row * 96 + 80 + s2]);
  for (int d = threadIdx.x; d < 2048; d += 256) {
    const size_t idx = (size_t)row * 2048 + d;
    const float delta = softplus(b2f(du[idx]) + ldin(dtb, dtboff + d, f));
    const float xcv = b2f(xc[idx]);
    const float y = delta * xcv * bc + xcv * ldin(Dp, dpoff + d, f);
    du[idx] = f2b(y * b2f(zsil[idx]));
  }
}

// ---------------------------------------------------------------------------
extern "C" void kernel_launch(void* const* d_in, const int* in_sizes, int n_in,
                              void* d_out, int out_size, void* d_ws, size_t ws_size,
                              hipStream_t stream)
{
  const void* img_feat = d_in[0];
  const void* txt_feat = d_in[1];
  const void* img_w    = d_in[2];
  const void* img_b    = d_in[3];
  const void* img_g    = d_in[4];
  const void* img_lb   = d_in[5];
  const void* txt_w    = d_in[6];
  const void* txt_b    = d_in[7];
  const void* txt_g    = d_in[8];
  const void* txt_lb   = d_in[9];
  const void* gate_w1  = d_in[10];
  const void* gate_b1  = d_in[11];
  const void* gate_w2  = d_in[12];
  const void* gate_b2  = d_in[13];
  const void* gate_w3  = d_in[14];
  const void* gate_b3  = d_in[15];
  const void* in_proj_w = d_in[16];
  const void* conv_w   = d_in[17];
  const void* conv_b   = d_in[18];
  const void* x_proj_w = d_in[19];
  const void* dt_proj_w = d_in[20];
  const void* dt_proj_b = d_in[21];
  // d_in[22] = A_log: multiplied by h0=0 at L=1 -> unused
  const void* D_param  = d_in[23];
  const void* out_proj_w = d_in[24];
  const void* mnorm_g  = d_in[25];
  const void* mnorm_b  = d_in[26];
  const void* fc_w     = d_in[27];
  const void* fc_b     = d_in[28];
  const void* final_g  = d_in[29];
  const void* final_b  = d_in[30];

  char* ws = (char*)d_ws;
  int*  flag = (int*)ws;
  char* base = ws + 256;

  // pick largest batch chunk whose ws footprint (256 + Bc*16384 B) fits
  const size_t avail = (ws_size > 256) ? ws_size - 256 : 0;
  int Bc = 64;
  for (int c = 1024; c >= 64; c >>= 1)
    if ((size_t)c * 16384 <= avail) { Bc = c; break; }

  // per-chunk region map (bytes from base):
  //  [0, Bc*2048)           xbuf
  //  [Bc*2048, Bc*4096)     cat (later dbc)
  //  [Bc*4096, Bc*8192)     P2: tA|tB, later xc, later mo/fcb
  //  [Bc*8192, Bc*12288)    P3: h1|h2|gate_f, later zs
  //  [Bc*12288, Bc*16384)   P4: du
  bf16* xbuf = (bf16*)base;
  bf16* cat  = (bf16*)(base + (size_t)Bc * 2048);
  bf16* dbc  = cat;
  char* P2   = base + (size_t)Bc * 4096;
  char* P3   = base + (size_t)Bc * 8192;
  char* P4   = base + (size_t)Bc * 12288;
  bf16* tA = (bf16*)P2;
  bf16* tB = (bf16*)(P2 + (size_t)Bc * 1024);
  bf16* xc = (bf16*)P2;
  bf16* mo = (bf16*)P2;
  bf16* fcb = (bf16*)P2;
  bf16* h1 = (bf16*)P3;
  bf16* h2 = (bf16*)(P3 + (size_t)Bc * 1024);
  float* gate_f = (float*)(P3 + (size_t)Bc * 1536);
  bf16* zs = (bf16*)P3;
  bf16* du = (bf16*)P4;

  hipLaunchKernelGGL(detect_kernel, dim3(1), dim3(64), 0, stream,
                     (const unsigned short*)img_g, flag);

  auto gemm = [&](const void* X, size_t xoff, int lda, int x_is_input,
                  const void* Wp, size_t woff, int ldw,
                  const void* bias, size_t boff,
                  const void* scale4, size_t soff,
                  bf16* Cp, int ldc, int M, int N, int K, int act) {
    dim3 grid((N + 63) / 64, (M + 63) / 64);
    hipLaunchKernelGGL(gemm_mfma, grid, dim3(256), 0, stream,
                       X, xoff, lda, Wp, woff, ldw, bias, boff, scale4, soff,
                       Cp, ldc, M, N, K, act, (const int*)flag, x_is_input);
  };

  for (int row0 = 0; row0 < 1024; row0 += Bc) {
    // ---- align (img -> cat cols [0,512); txt -> [512,1024))
    for (int mod = 0; mod < 2; ++mod) {
      const void* feat = mod ? txt_feat : img_feat;
      const void* Wm   = mod ? txt_w : img_w;
      const void* Bm   = mod ? txt_b : img_b;
      const void* Gm   = mod ? txt_g : img_g;
      const void* LBm  = mod ? txt_lb : img_lb;
      for (int i = 0; i < 3; ++i) {
        const void* Xp = (i == 0) ? feat : (const void*)tB;
        const size_t xo = (i == 0) ? (size_t)row0 * 512 : 0;
        const int xin = (i == 0) ? 1 : 0;
        gemm(Xp, xo, 512, xin, Wm, (size_t)i * 262144, 512,
             Bm, (size_t)i * 512, nullptr, 0, tA, 512, Bc, 512, 512, 1);
        if (i < 2)
          hipLaunchKernelGGL(ln_kernel, dim3(Bc), dim3(256), 0, stream,
                             tA, 512, (void*)tB, (size_t)0, 512, 0,
                             Gm, (size_t)i * 512, LBm, (size_t)i * 512, 512,
                             (const int*)flag);
        else
          hipLaunchKernelGGL(ln_kernel, dim3(Bc), dim3(256), 0, stream,
                             tA, 512, (void*)cat, (size_t)(mod * 512), 1024, 0,
                             Gm, (size_t)i * 512, LBm, (size_t)i * 512, 512,
                             (const int*)flag);
      }
    }

    // ---- gate MLP + softmax + combine
    gemm(cat, 0, 1024, 0, gate_w1, 0, 1024, gate_b1, 0, nullptr, 0,
         h1, 512, Bc, 512, 1024, 1);
    gemm(h1, 0, 512, 0, gate_w2, 0, 512, gate_b2, 0, nullptr, 0,
         h2, 256, Bc, 256, 512, 1);
    hipLaunchKernelGGL(gate3_kernel, dim3(Bc), dim3(256), 0, stream,
                       h2, gate_w3, gate_b3, gate_f,
                       d_out, (size_t)262144 + (size_t)row0 * 2,
                       (const int*)flag);
    hipLaunchKernelGGL(combine_kernel, dim3(Bc * 4), dim3(256), 0, stream,
                       cat, gate_f, xbuf);

    // ---- 3 mamba layers (L=1 collapsed)
    for (int i = 0; i < 3; ++i) {
      // xc = silu(conv_w[:,3]*(x @ inW_xc^T) + conv_b)
      gemm(xbuf, 0, 1024, 0, in_proj_w, (size_t)i * 4194304, 1024,
           conv_b, (size_t)i * 2048, conv_w, (size_t)i * 8192,
           xc, 2048, Bc, 2048, 1024, 2);
      // zs = silu(x @ inW_z^T)
      gemm(xbuf, 0, 1024, 0, in_proj_w,
           (size_t)i * 4194304 + (size_t)2048 * 1024, 1024,
           nullptr, 0, nullptr, 0, zs, 2048, Bc, 2048, 1024, 3);
      // dbc = xc @ x_proj^T  (dt[0:64] | B[64:80] | C[80:96])
      gemm(xc, 0, 2048, 0, x_proj_w, (size_t)i * 196608, 2048,
           nullptr, 0, nullptr, 0, dbc, 96, Bc, 96, 2048, 0);
      // du = dt @ dt_proj^T (raw)
      gemm(dbc, 0, 96, 0, dt_proj_w, (size_t)i * 131072, 64,
           nullptr, 0, nullptr, 0, du, 2048, Bc, 2048, 64, 0);
      // du := (softplus(du+dtb)*xc*(B.C) + xc*D) * zs
      hipLaunchKernelGGL(mamba_y_kernel, dim3(Bc), dim3(256), 0, stream,
                         du, dt_proj_b, (size_t)i * 2048, xc, zs, dbc,
                         D_param, (size_t)i * 2048, (const int*)flag);
      // mo = du @ out_proj^T  (mo aliases xc; xc dead after mamba_y)
      gemm(du, 0, 2048, 0, out_proj_w, (size_t)i * 2097152, 2048,
           nullptr, 0, nullptr, 0, mo, 1024, Bc, 1024, 2048, 0);
      // xbuf = LN(mo + xbuf)
      hipLaunchKernelGGL(addln_kernel, dim3(Bc), dim3(256), 0, stream,
                         mo, xbuf, xbuf, mnorm_g, (size_t)i * 1024,
                         mnorm_b, (size_t)i * 1024, (const int*)flag);
    }

    // ---- final fc + LN -> d_out (flag dtype)
    gemm(xbuf, 0, 1024, 0, fc_w, 0, 1024, fc_b, 0, nullptr, 0,
         fcb, 256, Bc, 256, 1024, 0);
    hipLaunchKernelGGL(ln_kernel, dim3(Bc), dim3(256), 0, stream,
                       fcb, 256, d_out, (size_t)row0 * 256, 256, 1,
                       final_g, 0, final_b, 0, 256, (const int*)flag);
  }
}

// Round 6
// 488.796 us; speedup vs baseline: 2.1397x; 2.1397x over previous
//
#include <hip/hip_runtime.h>
#include <hip/hip_bf16.h>

typedef __attribute__((ext_vector_type(8))) short short8;
typedef __attribute__((ext_vector_type(4))) float floatx4;
typedef __hip_bfloat16 bf16;

__device__ __forceinline__ float b2f(bf16 v) { return __bfloat162float(v); }
__device__ __forceinline__ bf16 f2b(float v) { return __float2bfloat16(v); }
__device__ __forceinline__ short f2s(float v) {
  union { bf16 b; short s; } u; u.b = f2b(v); return u.s;
}

// flag: 1 = d_in tensors are f32 (reference dtype), 0 = bf16
__device__ __forceinline__ float ldin(const void* p, size_t i, int f) {
  return f ? ((const float*)p)[i] : b2f(((const bf16*)p)[i]);
}
template<bool F>
__device__ __forceinline__ float ldinT(const void* p, size_t i) {
  if constexpr (F) return ((const float*)p)[i];
  else return b2f(((const bf16*)p)[i]);
}
__device__ __forceinline__ void stout(void* p, size_t i, float v, int f32) {
  if (f32) ((float*)p)[i] = v;
  else ((bf16*)p)[i] = f2b(v);
}
template<bool F>
__device__ __forceinline__ short8 ldfrag(const void* base, size_t off) {
  if constexpr (F) {
    const float* p = (const float*)base + off;
    const floatx4 lo = *(const floatx4*)p;
    const floatx4 hi = *(const floatx4*)(p + 4);
    short8 r;
    r[0] = f2s(lo[0]); r[1] = f2s(lo[1]); r[2] = f2s(lo[2]); r[3] = f2s(lo[3]);
    r[4] = f2s(hi[0]); r[5] = f2s(hi[1]); r[6] = f2s(hi[2]); r[7] = f2s(hi[3]);
    return r;
  } else {
    return *(const short8*)((const bf16*)base + off);
  }
}

__device__ __forceinline__ float silu(float v) {
  const float e = expf(-fabsf(v));
  const float sig = (v >= 0.f) ? 1.f / (1.f + e) : e / (1.f + e);
  return v * sig;
}
__device__ __forceinline__ float softplus(float v) {
  return fmaxf(v, 0.f) + log1pf(expf(-fabsf(v)));
}

// dtype probe: img_ln_g is all-ones. bf16 -> u16[0]==0x3F80; f32 -> 0x0000.
__global__ void detect_kernel(const unsigned short* __restrict__ probe,
                              int* __restrict__ flag) {
  if (threadIdx.x == 0 && blockIdx.x == 0)
    *flag = (probe[0] == (unsigned short)0x3F80) ? 0 : 1;
}

// ---------------------------------------------------------------------------
// Weight/feature pre-conversion: 11 contiguously-packed segments -> bf16.
// ---------------------------------------------------------------------------
struct CTab {
  const void* src[11];
  unsigned cum8[12];   // starting chunk (8 elems) per segment; [11] = total
};
__global__ __launch_bounds__(256) void conv_kernel(
    CTab tab, bf16* __restrict__ dst, const int* __restrict__ flagp) {
  const int f = *flagp;
  unsigned i = blockIdx.x * 256 + threadIdx.x;
  const unsigned stride = gridDim.x * 256;
  for (; i < tab.cum8[11]; i += stride) {
    int s = 0;
#pragma unroll
    for (int k = 1; k < 11; ++k)
      if (i >= tab.cum8[k]) s = k;
    const size_t loc = (size_t)(i - tab.cum8[s]) * 8;
    bf16* d = dst + (size_t)i * 8;
    if (f) {
      const float* p = (const float*)tab.src[s] + loc;
      floatx4 lo = *(const floatx4*)p;
      floatx4 hi = *(const floatx4*)(p + 4);
      short8 o;
      o[0]=f2s(lo[0]); o[1]=f2s(lo[1]); o[2]=f2s(lo[2]); o[3]=f2s(lo[3]);
      o[4]=f2s(hi[0]); o[5]=f2s(hi[1]); o[6]=f2s(hi[2]); o[7]=f2s(hi[3]);
      *(short8*)d = o;
    } else {
      *(short8*)d = *(const short8*)((const bf16*)tab.src[s] + loc);
    }
  }
}

// ---------------------------------------------------------------------------
// Fast LDS-staged GEMM: C[M,N] = epi(A[M,K] @ W[N,K]^T)
// Block: 256 thr = 4 waves, 64x64 C-tile, BK=64, double-buffered LDS,
// XOR-swizzled 16B chunks (2-way max bank conflict on ds_read_b128).
// Dual-source: blocks with n_base >= nsplit use A1/W1 (align img|txt fusion).
// act: 0 +bias(opt)  1 relu(+bias)  3 silu  4 fused-xz  5 raw f32 to Cf (splitK)
// ---------------------------------------------------------------------------
__global__ __launch_bounds__(256) void gemm_lds(
    const bf16* __restrict__ A0, const bf16* __restrict__ A1, int lda,
    const bf16* __restrict__ W0, const bf16* __restrict__ W1, int ldw,
    int nsplit,
    const void* __restrict__ bias0, size_t boff0,
    const void* __restrict__ bias1, size_t boff1,
    const void* __restrict__ scale4, size_t soff,
    bf16* __restrict__ C, bf16* __restrict__ C2, int ldc,
    float* __restrict__ Cf,
    int M, int N, int Ksz, int act,
    const int* __restrict__ flagp)
{
  __shared__ bf16 As[2][4096];
  __shared__ bf16 Bs[2][4096];
  const int t = threadIdx.x;
  const int lane = t & 63, w = t >> 6;
  const int m_base = blockIdx.y * 64;
  const int n_base = blockIdx.x * 64;
  const int kz = blockIdx.z;
  const size_t kb0 = (size_t)kz * Ksz;

  const bool alt = (n_base >= nsplit);
  const bf16* Ap = alt ? A1 : A0;
  const bf16* Wp = alt ? W1 : W0;
  const int wrb = alt ? (n_base - nsplit) : n_base;
  const int wmax = (alt ? (N - nsplit) : (nsplit < N ? nsplit : N)) - 1;

  const int r_ = t >> 3;    // staging: chunk L = c*256+t -> row c*32 + (t>>3)
  const int cc_ = t & 7;

  const int T = Ksz >> 6;
  const int lr = lane & 15, q = lane >> 4;
  const int aw = (w >> 1) * 32, bw = (w & 1) * 32;

  floatx4 acc00 = {0.f,0.f,0.f,0.f};
  floatx4 acc01 = acc00, acc10 = acc00, acc11 = acc00;

  auto stage = [&](int b, int kt) {
    const size_t kb = kb0 + (size_t)kt * 64;
#pragma unroll
    for (int c = 0; c < 2; ++c) {
      const int L = c * 256 + t;
      const int r = c * 32 + r_;
      const int scc = cc_ ^ (r & 7);   // source col-chunk for LDS chunk (r,cc)
      {
        const int row = min(m_base + r, M - 1);
        *(short8*)(&As[b][L * 8]) =
            *(const short8*)(Ap + (size_t)row * lda + kb + scc * 8);
      }
      {
        const int row = min(wrb + r, wmax);
        *(short8*)(&Bs[b][L * 8]) =
            *(const short8*)(Wp + (size_t)row * ldw + kb + scc * 8);
      }
    }
  };

  stage(0, 0);
  int buf = 0;
  for (int kt = 0; kt < T; ++kt) {
    __syncthreads();               // staged buf ready; prev reads done
    if (kt + 1 < T) stage(buf ^ 1, kt + 1);
    const bf16* as = As[buf];
    const bf16* bs = Bs[buf];
#pragma unroll
    for (int kw = 0; kw < 2; ++kw) {
      const int kc = kw * 4 + q;
      const int ar0 = aw + lr, ar1 = ar0 + 16;
      const int br0 = bw + lr, br1 = br0 + 16;
      short8 a0 = *(const short8*)(as + ((ar0 * 8 + (kc ^ (ar0 & 7))) * 8));
      short8 a1 = *(const short8*)(as + ((ar1 * 8 + (kc ^ (ar1 & 7))) * 8));
      short8 b0 = *(const short8*)(bs + ((br0 * 8 + (kc ^ (br0 & 7))) * 8));
      short8 b1 = *(const short8*)(bs + ((br1 * 8 + (kc ^ (br1 & 7))) * 8));
      acc00 = __builtin_amdgcn_mfma_f32_16x16x32_bf16(a0, b0, acc00, 0, 0, 0);
      acc01 = __builtin_amdgcn_mfma_f32_16x16x32_bf16(a0, b1, acc01, 0, 0, 0);
      acc10 = __builtin_amdgcn_mfma_f32_16x16x32_bf16(a1, b0, acc10, 0, 0, 0);
      acc11 = __builtin_amdgcn_mfma_f32_16x16x32_bf16(a1, b1, acc11, 0, 0, 0);
    }
    buf ^= 1;
  }

  const int f = *flagp;
  floatx4 acs[2][2] = {{acc00, acc01}, {acc10, acc11}};
#pragma unroll
  for (int im = 0; im < 2; ++im) {
#pragma unroll
    for (int jn = 0; jn < 2; ++jn) {
      const int n = n_base + bw + jn * 16 + lr;
      if (n >= N) continue;
#pragma unroll
      for (int r = 0; r < 4; ++r) {
        const int m = m_base + aw + im * 16 + q * 4 + r;
        float v = acs[im][jn][r];
        if (act == 5) {
          Cf[(size_t)kz * M * ldc + (size_t)m * ldc + n] = v;
        } else if (act == 4) {
          if (n < 2048) {
            const float sv = ldin(scale4, soff + (size_t)n * 4 + 3, f);
            const float bv = ldin(bias0, boff0 + n, f);
            C[(size_t)m * ldc + n] = f2b(silu(v * sv + bv));
          } else {
            C2[(size_t)m * ldc + (n - 2048)] = f2b(silu(v));
          }
        } else {
          float bv = 0.f;
          if (bias0) bv = alt ? ldin(bias1, boff1 + (n - nsplit), f)
                              : ldin(bias0, boff0 + n, f);
          v += bv;
          if (act == 1) v = fmaxf(v, 0.f);
          else if (act == 3) v = silu(v);
          C[(size_t)m * ldc + n] = f2b(v);
        }
      }
    }
  }
}

// ---------------------------------------------------------------------------
// Legacy register-direct GEMM (fallback path; round-5 verified)
// ---------------------------------------------------------------------------
template<bool XF, bool WF>
__device__ __forceinline__ void gemm_body(
    const void* __restrict__ X, int lda,
    const void* __restrict__ W, int ldw,
    const void* __restrict__ bias, const void* __restrict__ scale4,
    bf16* __restrict__ C, int ldc,
    int M, int N, int K, int act,
    int m_base, int n_base, int lane)
{
  const int lr = lane & 15;
  const int kq = (lane >> 4) * 8;
  const int ma0 = min(m_base + lr, M - 1);
  const int ma1 = min(m_base + 16 + lr, M - 1);
  const int nb0 = min(n_base + lr, N - 1);
  const int nb1 = min(n_base + 16 + lr, N - 1);
  const size_t ox0 = (size_t)ma0 * lda + kq;
  const size_t ox1 = (size_t)ma1 * lda + kq;
  const size_t ow0 = (size_t)nb0 * ldw + kq;
  const size_t ow1 = (size_t)nb1 * ldw + kq;
  floatx4 acc00 = {0.f,0.f,0.f,0.f};
  floatx4 acc01 = acc00, acc10 = acc00, acc11 = acc00;
  for (int k0 = 0; k0 < K; k0 += 32) {
    short8 a0 = ldfrag<XF>(X, ox0 + k0);
    short8 a1 = ldfrag<XF>(X, ox1 + k0);
    short8 b0 = ldfrag<WF>(W, ow0 + k0);
    short8 b1 = ldfrag<WF>(W, ow1 + k0);
    acc00 = __builtin_amdgcn_mfma_f32_16x16x32_bf16(a0, b0, acc00, 0, 0, 0);
    acc01 = __builtin_amdgcn_mfma_f32_16x16x32_bf16(a0, b1, acc01, 0, 0, 0);
    acc10 = __builtin_amdgcn_mfma_f32_16x16x32_bf16(a1, b0, acc10, 0, 0, 0);
    acc11 = __builtin_amdgcn_mfma_f32_16x16x32_bf16(a1, b1, acc11, 0, 0, 0);
  }
  const int colx = lane & 15;
  const int rq = (lane >> 4) * 4;
  floatx4 accs[2][2] = {{acc00, acc01}, {acc10, acc11}};
#pragma unroll
  for (int im = 0; im < 2; ++im) {
#pragma unroll
    for (int jn = 0; jn < 2; ++jn) {
      const int n = n_base + jn * 16 + colx;
      if (n >= N) continue;
      const float bv = bias ? ldinT<WF>(bias, n) : 0.f;
      const float sv = (act == 2) ? ldinT<WF>(scale4, (size_t)n * 4 + 3) : 1.f;
#pragma unroll
      for (int r = 0; r < 4; ++r) {
        const int m = m_base + im * 16 + rq + r;
        if (m >= M) continue;
        float v = accs[im][jn][r];
        if (act == 2) v = silu(v * sv + bv);
        else if (act == 3) v = silu(v);
        else { v += bv; if (act == 1) v = fmaxf(v, 0.f); }
        C[(size_t)m * ldc + n] = f2b(v);
      }
    }
  }
}

__global__ __launch_bounds__(256) void gemm_mfma(
    const void* __restrict__ X, size_t xoff, int lda,
    const void* __restrict__ W, size_t woff, int ldw,
    const void* __restrict__ bias, size_t boff,
    const void* __restrict__ scale4, size_t soff,
    bf16* __restrict__ C, int ldc,
    int M, int N, int K, int act,
    const int* __restrict__ flagp, int x_is_input)
{
  const int lane = threadIdx.x & 63;
  const int wave = threadIdx.x >> 6;
  const int m_base = blockIdx.y * 64 + (wave >> 1) * 32;
  const int n_base = blockIdx.x * 64 + (wave & 1) * 32;
  const int f = *flagp;
  if (f) {
    const float* Wf = (const float*)W + woff;
    const float* bp = bias ? (const float*)bias + boff : nullptr;
    const float* sp = scale4 ? (const float*)scale4 + soff : nullptr;
    if (x_is_input)
      gemm_body<true, true>((const float*)X + xoff, lda, Wf, ldw, bp, sp,
                            C, ldc, M, N, K, act, m_base, n_base, lane);
    else
      gemm_body<false, true>((const bf16*)X + xoff, lda, Wf, ldw, bp, sp,
                             C, ldc, M, N, K, act, m_base, n_base, lane);
  } else {
    const bf16* Wb = (const bf16*)W + woff;
    const bf16* bp = bias ? (const bf16*)bias + boff : nullptr;
    const bf16* sp = scale4 ? (const bf16*)scale4 + soff : nullptr;
    gemm_body<false, false>((const bf16*)X + xoff, lda, Wb, ldw, bp, sp,
                            C, ldc, M, N, K, act, m_base, n_base, lane);
  }
}

// ---------------------------------------------------------------------------
__device__ __forceinline__ void block_reduce2(float& a, float& b) {
#pragma unroll
  for (int off = 32; off > 0; off >>= 1) {
    a += __shfl_down(a, off, 64);
    b += __shfl_down(b, off, 64);
  }
  __shared__ float sa[4], sb[4];
  const int lane = threadIdx.x & 63;
  const int wv = threadIdx.x >> 6;
  if (lane == 0) { sa[wv] = a; sb[wv] = b; }
  __syncthreads();
  a = sa[0] + sa[1] + sa[2] + sa[3];
  b = sb[0] + sb[1] + sb[2] + sb[3];
}

__global__ __launch_bounds__(256) void ln_kernel(
    const bf16* __restrict__ in, int in_ld,
    void* __restrict__ out, size_t out_eoff, int out_ld, int out_mode,
    const void* __restrict__ g, size_t goff,
    const void* __restrict__ b, size_t boff, int N,
    const int* __restrict__ flagp)
{
  __shared__ float vals[1024];
  const int f = *flagp;
  const int row = blockIdx.x;
  const bf16* ip = in + (size_t)row * in_ld;
  float s = 0.f, ss = 0.f;
  for (int j = threadIdx.x; j < N; j += 256) {
    float v = b2f(ip[j]);
    vals[j] = v; s += v; ss += v * v;
  }
  block_reduce2(s, ss);
  const float mean = s / N;
  const float inv = rsqrtf(fmaxf(ss / N - mean * mean, 0.f) + 1e-5f);
  const int of32 = out_mode ? f : 0;
  for (int j = threadIdx.x; j < N; j += 256) {
    const float v = (vals[j] - mean) * inv * ldin(g, goff + j, f) +
                    ldin(b, boff + j, f);
    stout(out, out_eoff + (size_t)row * out_ld + j, v, of32);
  }
}

// dual-modality LN for fused align: rows [Bc], y in {0,1} selects 512-col half
__global__ __launch_bounds__(256) void ln_dual(
    const bf16* __restrict__ in, bf16* __restrict__ out,
    const void* __restrict__ g0, size_t g0o, const void* __restrict__ b0, size_t b0o,
    const void* __restrict__ g1, size_t g1o, const void* __restrict__ b1, size_t b1o,
    const int* __restrict__ flagp)
{
  __shared__ float vals[512];
  const int f = *flagp;
  const int row = blockIdx.x, y = blockIdx.y;
  const bf16* ip = in + (size_t)row * 1024 + y * 512;
  float s = 0.f, ss = 0.f;
  for (int j = threadIdx.x; j < 512; j += 256) {
    float v = b2f(ip[j]);
    vals[j] = v; s += v; ss += v * v;
  }
  block_reduce2(s, ss);
  const float mean = s / 512.f;
  const float inv = rsqrtf(fmaxf(ss / 512.f - mean * mean, 0.f) + 1e-5f);
  const void* g = y ? g1 : g0; const size_t go = y ? g1o : g0o;
  const void* b = y ? b1 : b0; const size_t bo = y ? b1o : b0o;
  bf16* op = out + (size_t)row * 1024 + y * 512;
  for (int j = threadIdx.x; j < 512; j += 256)
    op[j] = f2b((vals[j] - mean) * inv * ldin(g, go + j, f) +
                ldin(b, bo + j, f));
}

__global__ __launch_bounds__(256) void addln_kernel(
    const bf16* __restrict__ mo, const bf16* __restrict__ xres,
    bf16* __restrict__ out,
    const void* __restrict__ g, size_t goff,
    const void* __restrict__ b, size_t boff,
    const int* __restrict__ flagp)
{
  __shared__ float vals[1024];
  const int f = *flagp;
  const int row = blockIdx.x;
  float s = 0.f, ss = 0.f;
  for (int j = threadIdx.x; j < 1024; j += 256) {
    float v = b2f(mo[(size_t)row * 1024 + j]) + b2f(xres[(size_t)row * 1024 + j]);
    vals[j] = v; s += v; ss += v * v;
  }
  block_reduce2(s, ss);
  const float mean = s / 1024.f;
  const float inv = rsqrtf(fmaxf(ss / 1024.f - mean * mean, 0.f) + 1e-5f);
  for (int j = threadIdx.x; j < 1024; j += 256)
    out[(size_t)row * 1024 + j] =
        f2b((vals[j] - mean) * inv * ldin(g, goff + j, f) +
            ldin(b, boff + j, f));
}

// residual-add LN with two f32 split-K partials (fast out_proj path); in-place
__global__ __launch_bounds__(256) void addln2_kernel(
    const float* __restrict__ moA, const float* __restrict__ moB,
    bf16* __restrict__ x,
    const void* __restrict__ g, size_t goff,
    const void* __restrict__ b, size_t boff,
    const int* __restrict__ flagp)
{
  __shared__ float vals[1024];
  const int f = *flagp;
  const int row = blockIdx.x;
  float s = 0.f, ss = 0.f;
  for (int j = threadIdx.x; j < 1024; j += 256) {
    const size_t idx = (size_t)row * 1024 + j;
    float v = moA[idx] + moB[idx] + b2f(x[idx]);
    vals[j] = v; s += v; ss += v * v;
  }
  block_reduce2(s, ss);
  const float mean = s / 1024.f;
  const float inv = rsqrtf(fmaxf(ss / 1024.f - mean * mean, 0.f) + 1e-5f);
  for (int j = threadIdx.x; j < 1024; j += 256)
    x[(size_t)row * 1024 + j] =
        f2b((vals[j] - mean) * inv * ldin(g, goff + j, f) +
            ldin(b, boff + j, f));
}

__global__ __launch_bounds__(256) void gate3_kernel(
    const bf16* __restrict__ h2, const void* __restrict__ w3,
    const void* __restrict__ b3, float* __restrict__ gate_f,
    void* __restrict__ gate_out, size_t gout_eoff,
    const int* __restrict__ flagp)
{
  const int f = *flagp;
  const int row = blockIdx.x;
  const int t = threadIdx.x;
  const float h = b2f(h2[(size_t)row * 256 + t]);
  float p0 = h * ldin(w3, t, f);
  float p1 = h * ldin(w3, 256 + t, f);
  block_reduce2(p0, p1);
  if (t == 0) {
    const float l0 = p0 + ldin(b3, 0, f);
    const float l1 = p1 + ldin(b3, 1, f);
    const float mx = fmaxf(l0, l1);
    const float e0 = expf(l0 - mx), e1 = expf(l1 - mx);
    const float g0 = e0 / (e0 + e1), g1 = e1 / (e0 + e1);
    gate_f[row * 2] = g0;
    gate_f[row * 2 + 1] = g1;
    stout(gate_out, gout_eoff + (size_t)row * 2 + 0, g0, f);
    stout(gate_out, gout_eoff + (size_t)row * 2 + 1, g1, f);
  }
}

__global__ __launch_bounds__(256) void combine_kernel(
    const bf16* __restrict__ cat, const float* __restrict__ gate_f,
    bf16* __restrict__ x)
{
  const int t = blockIdx.x * 256 + threadIdx.x;
  const int bidx = t >> 10, j = t & 1023;
  x[t] = f2b(gate_f[bidx * 2 + (j >> 9)] * b2f(cat[t]));
}

// sum 4 f32 split-K partials -> bf16 (x_proj fixup)
__global__ __launch_bounds__(256) void fix4_kernel(
    const float* __restrict__ p, bf16* __restrict__ o, int cnt, int seg)
{
  const int i = blockIdx.x * 256 + threadIdx.x;
  if (i < cnt)
    o[i] = f2b(p[i] + p[i + seg] + p[i + 2 * seg] + p[i + 3 * seg]);
}

__global__ __launch_bounds__(256) void mamba_y_kernel(
    bf16* __restrict__ du, const void* __restrict__ dtb, size_t dtboff,
    const bf16* __restrict__ xc, const bf16* __restrict__ zsil,
    const bf16* __restrict__ dbc, const void* __restrict__ Dp, size_t dpoff,
    const int* __restrict__ flagp)
{
  const int f = *flagp;
  const int row = blockIdx.x;
  float bc = 0.f;
#pragma unroll
  for (int s2 = 0; s2 < 16; ++s2)
    bc += b2f(dbc[row * 96 + 64 + s2]) * b2f(dbc[row * 96 + 80 + s2]);
  for (int d = threadIdx.x; d < 2048; d += 256) {
    const size_t idx = (size_t)row * 2048 + d;
    const float delta = softplus(b2f(du[idx]) + ldin(dtb, dtboff + d, f));
    const float xcv = b2f(xc[idx]);
    const float y = delta * xcv * bc + xcv * ldin(Dp, dpoff + d, f);
    du[idx] = f2b(y * b2f(zsil[idx]));
  }
}

// ---------------------------------------------------------------------------
extern "C" void kernel_launch(void* const* d_in, const int* in_sizes, int n_in,
                              void* d_out, int out_size, void* d_ws, size_t ws_size,
                              hipStream_t stream)
{
  const void* img_feat = d_in[0];
  const void* txt_feat = d_in[1];
  const void* img_w    = d_in[2];
  const void* img_b    = d_in[3];
  const void* img_g    = d_in[4];
  const void* img_lb   = d_in[5];
  const void* txt_w    = d_in[6];
  const void* txt_b    = d_in[7];
  const void* txt_g    = d_in[8];
  const void* txt_lb   = d_in[9];
  const void* gate_w1  = d_in[10];
  const void* gate_b1  = d_in[11];
  const void* gate_w2  = d_in[12];
  const void* gate_b2  = d_in[13];
  const void* gate_w3  = d_in[14];
  const void* gate_b3  = d_in[15];
  const void* in_proj_w = d_in[16];
  const void* conv_w   = d_in[17];
  const void* conv_b   = d_in[18];
  const void* x_proj_w = d_in[19];
  const void* dt_proj_w = d_in[20];
  const void* dt_proj_b = d_in[21];
  // d_in[22] = A_log: multiplied by h0=0 at L=1 -> unused
  const void* D_param  = d_in[23];
  const void* out_proj_w = d_in[24];
  const void* mnorm_g  = d_in[25];
  const void* mnorm_b  = d_in[26];
  const void* fc_w     = d_in[27];
  const void* fc_b     = d_in[28];
  const void* final_g  = d_in[29];
  const void* final_b  = d_in[30];

  char* ws = (char*)d_ws;
  int*  flag = (int*)ws;
  hipLaunchKernelGGL(detect_kernel, dim3(1), dim3(64), 0, stream,
                     (const unsigned short*)img_g, flag);

  // ---- fast-path ws budget: 256 + conv(46.8MB) + 32456*Bc
  const size_t CONV_BYTES = 46792704;   // 23396352 bf16 elems
  int BcF = 0;
  for (int c = 1024; c >= 64; c >>= 1)
    if (256 + CONV_BYTES + (size_t)32456 * c <= ws_size) { BcF = c; break; }

  if (BcF > 0) {
    // ================= FAST PATH =================
    const int Bc = BcF;
    bf16* conv = (bf16*)(ws + 256);
    CTab tab;
    const void* srcs[11] = {img_feat, txt_feat, img_w, txt_w, gate_w1, gate_w2,
                            in_proj_w, x_proj_w, dt_proj_w, out_proj_w, fc_w};
    const unsigned cnts[11] = {524288u, 524288u, 786432u, 786432u, 524288u,
                               131072u, 12582912u, 589824u, 393216u,
                               6291456u, 262144u};
    unsigned cum = 0;
    for (int s = 0; s < 11; ++s) { tab.src[s] = srcs[s]; tab.cum8[s] = cum; cum += cnts[s] / 8; }
    tab.cum8[11] = cum;
    bf16* cImgF = conv;
    bf16* cTxtF = conv + 524288;
    bf16* cImgW = conv + 1048576;
    bf16* cTxtW = conv + 1835008;
    bf16* cGw1  = conv + 2621440;
    bf16* cGw2  = conv + 3145728;
    bf16* cInpj = conv + 3276800;
    bf16* cXpj  = conv + 15859712;
    bf16* cDtpj = conv + 16449536;
    bf16* cOutp = conv + 16842752;
    bf16* cFc   = conv + 23134208;

    hipLaunchKernelGGL(conv_kernel, dim3(8192), dim3(256), 0, stream,
                       tab, conv, (const int*)flag);

    char* act = ws + 256 + CONV_BYTES;
    bf16*  cat   = (bf16*)(act);
    bf16*  tmpA  = (bf16*)(act + (size_t)2048 * Bc);
    bf16*  tmpB  = (bf16*)(act + (size_t)4096 * Bc);
    bf16*  xbuf  = (bf16*)(act + (size_t)6144 * Bc);
    bf16*  xc    = (bf16*)(act + (size_t)8192 * Bc);
    bf16*  zs    = (bf16*)(act + (size_t)12288 * Bc);
    bf16*  du    = (bf16*)(act + (size_t)16384 * Bc);
    float* moP   = (float*)(act + (size_t)20480 * Bc);
    float* xpjP  = (float*)(act + (size_t)28672 * Bc);
    bf16*  dbc   = (bf16*)(act + (size_t)30208 * Bc);
    bf16*  h1    = (bf16*)(act + (size_t)30400 * Bc);
    bf16*  h2    = (bf16*)(act + (size_t)31424 * Bc);
    float* gateF = (float*)(act + (size_t)31936 * Bc);
    bf16*  fcb   = (bf16*)(act + (size_t)31944 * Bc);
    const int NSINF = 1 << 30;

    auto G = [&](const bf16* A0p, const bf16* A1p, int lda,
                 const bf16* W0p, const bf16* W1p, int ldw, int nsplit,
                 const void* b0p, size_t b0o, const void* b1p, size_t b1o,
                 const void* s4, size_t s4o,
                 bf16* Cp, bf16* C2p, int ldc, float* Cfp,
                 int M_, int N_, int Ksz, int S, int actc) {
      dim3 grid((N_ + 63) / 64, M_ / 64, S);
      hipLaunchKernelGGL(gemm_lds, grid, dim3(256), 0, stream,
                         A0p, A1p, lda, W0p, W1p, ldw, nsplit,
                         b0p, b0o, b1p, b1o, s4, s4o,
                         Cp, C2p, ldc, Cfp, M_, N_, Ksz, actc,
                         (const int*)flag);
    };

    for (int row0 = 0; row0 < 1024; row0 += Bc) {
      // ---- fused align (img cols [0,512) | txt cols [512,1024))
      for (int i = 0; i < 3; ++i) {
        const bf16* A0p = (i == 0) ? cImgF + (size_t)row0 * 512 : tmpB;
        const bf16* A1p = (i == 0) ? cTxtF + (size_t)row0 * 512 : tmpB + 512;
        const int lda = (i == 0) ? 512 : 1024;
        G(A0p, A1p, lda, cImgW + (size_t)i * 262144, cTxtW + (size_t)i * 262144,
          512, 512, img_b, (size_t)i * 512, txt_b, (size_t)i * 512,
          nullptr, 0, tmpA, nullptr, 1024, nullptr, Bc, 1024, 512, 1, 1);
        bf16* lnout = (i < 2) ? tmpB : cat;
        hipLaunchKernelGGL(ln_dual, dim3(Bc, 2), dim3(256), 0, stream,
                           tmpA, lnout,
                           img_g, (size_t)i * 512, img_lb, (size_t)i * 512,
                           txt_g, (size_t)i * 512, txt_lb, (size_t)i * 512,
                           (const int*)flag);
      }

      // ---- gate MLP + softmax + combine
      G(cat, cat, 1024, cGw1, cGw1, 1024, NSINF, gate_b1, 0, gate_b1, 0,
        nullptr, 0, h1, nullptr, 512, nullptr, Bc, 512, 1024, 1, 1);
      G(h1, h1, 512, cGw2, cGw2, 512, NSINF, gate_b2, 0, gate_b2, 0,
        nullptr, 0, h2, nullptr, 256, nullptr, Bc, 256, 512, 1, 1);
      hipLaunchKernelGGL(gate3_kernel, dim3(Bc), dim3(256), 0, stream,
                         h2, gate_w3, gate_b3, gateF,
                         d_out, (size_t)262144 + (size_t)row0 * 2,
                         (const int*)flag);
      hipLaunchKernelGGL(combine_kernel, dim3(Bc * 4), dim3(256), 0, stream,
                         cat, gateF, xbuf);

      // ---- 3 mamba layers (L=1 collapsed)
      for (int i = 0; i < 3; ++i) {
        // fused xz: n<2048 -> xc=silu(v*cw+cb); n>=2048 -> zs=silu(v)
        G(xbuf, xbuf, 1024, cInpj + (size_t)i * 4194304,
          cInpj + (size_t)i * 4194304, 1024, NSINF,
          conv_b, (size_t)i * 2048, conv_b, (size_t)i * 2048,
          conv_w, (size_t)i * 8192,
          xc, zs, 2048, nullptr, Bc, 4096, 1024, 1, 4);
        // x_proj split-K=4 -> f32 partials -> dbc
        G(xc, xc, 2048, cXpj + (size_t)i * 196608, cXpj + (size_t)i * 196608,
          2048, NSINF, nullptr, 0, nullptr, 0, nullptr, 0,
          nullptr, nullptr, 96, xpjP, Bc, 96, 512, 4, 5);
        hipLaunchKernelGGL(fix4_kernel, dim3((Bc * 96 + 255) / 256), dim3(256),
                           0, stream, xpjP, dbc, Bc * 96, Bc * 96);
        // dt_proj (K=64) -> du raw
        G(dbc, dbc, 96, cDtpj + (size_t)i * 131072, cDtpj + (size_t)i * 131072,
          64, NSINF, nullptr, 0, nullptr, 0, nullptr, 0,
          du, nullptr, 2048, nullptr, Bc, 2048, 64, 1, 0);
        // du := (softplus(du+dtb)*xc*(B.C) + xc*D) * zs
        hipLaunchKernelGGL(mamba_y_kernel, dim3(Bc), dim3(256), 0, stream,
                           du, dt_proj_b, (size_t)i * 2048, xc, zs, dbc,
                           D_param, (size_t)i * 2048, (const int*)flag);
        // out_proj split-K=2 -> f32 partials; then residual+LN
        G(du, du, 2048, cOutp + (size_t)i * 2097152,
          cOutp + (size_t)i * 2097152, 2048, NSINF,
          nullptr, 0, nullptr, 0, nullptr, 0,
          nullptr, nullptr, 1024, moP, Bc, 1024, 1024, 2, 5);
        hipLaunchKernelGGL(addln2_kernel, dim3(Bc), dim3(256), 0, stream,
                           moP, moP + (size_t)Bc * 1024, xbuf,
                           mnorm_g, (size_t)i * 1024, mnorm_b, (size_t)i * 1024,
                           (const int*)flag);
      }

      // ---- final fc + LN -> d_out (flag dtype)
      G(xbuf, xbuf, 1024, cFc, cFc, 1024, NSINF, fc_b, 0, fc_b, 0,
        nullptr, 0, fcb, nullptr, 256, nullptr, Bc, 256, 1024, 1, 0);
      hipLaunchKernelGGL(ln_kernel, dim3(Bc), dim3(256), 0, stream,
                         fcb, 256, d_out, (size_t)row0 * 256, 256, 1,
                         final_g, 0, final_b, 0, 256, (const int*)flag);
    }
    return;
  }

  // ================= LEGACY PATH (round-5, small ws) =================
  char* base = ws + 256;
  const size_t avail = (ws_size > 256) ? ws_size - 256 : 0;
  int Bc = 64;
  for (int c = 1024; c >= 64; c >>= 1)
    if ((size_t)c * 16384 <= avail) { Bc = c; break; }

  bf16* xbuf = (bf16*)base;
  bf16* cat  = (bf16*)(base + (size_t)Bc * 2048);
  bf16* dbc  = cat;
  char* P2   = base + (size_t)Bc * 4096;
  char* P3   = base + (size_t)Bc * 8192;
  char* P4   = base + (size_t)Bc * 12288;
  bf16* tA = (bf16*)P2;
  bf16* tB = (bf16*)(P2 + (size_t)Bc * 1024);
  bf16* xc = (bf16*)P2;
  bf16* mo = (bf16*)P2;
  bf16* fcb = (bf16*)P2;
  bf16* h1 = (bf16*)P3;
  bf16* h2 = (bf16*)(P3 + (size_t)Bc * 1024);
  float* gate_f = (float*)(P3 + (size_t)Bc * 1536);
  bf16* zs = (bf16*)P3;
  bf16* du = (bf16*)P4;

  auto gemm = [&](const void* X, size_t xoff, int lda, int x_is_input,
                  const void* Wp, size_t woff, int ldw,
                  const void* bias, size_t boff,
                  const void* scale4, size_t soff,
                  bf16* Cp, int ldc, int M, int N, int K, int actc) {
    dim3 grid((N + 63) / 64, (M + 63) / 64);
    hipLaunchKernelGGL(gemm_mfma, grid, dim3(256), 0, stream,
                       X, xoff, lda, Wp, woff, ldw, bias, boff, scale4, soff,
                       Cp, ldc, M, N, K, actc, (const int*)flag, x_is_input);
  };

  for (int row0 = 0; row0 < 1024; row0 += Bc) {
    for (int mod = 0; mod < 2; ++mod) {
      const void* feat = mod ? txt_feat : img_feat;
      const void* Wm   = mod ? txt_w : img_w;
      const void* Bm   = mod ? txt_b : img_b;
      const void* Gm   = mod ? txt_g : img_g;
      const void* LBm  = mod ? txt_lb : img_lb;
      for (int i = 0; i < 3; ++i) {
        const void* Xp = (i == 0) ? feat : (const void*)tB;
        const size_t xo = (i == 0) ? (size_t)row0 * 512 : 0;
        const int xin = (i == 0) ? 1 : 0;
        gemm(Xp, xo, 512, xin, Wm, (size_t)i * 262144, 512,
             Bm, (size_t)i * 512, nullptr, 0, tA, 512, Bc, 512, 512, 1);
        if (i < 2)
          hipLaunchKernelGGL(ln_kernel, dim3(Bc), dim3(256), 0, stream,
                             tA, 512, (void*)tB, (size_t)0, 512, 0,
                             Gm, (size_t)i * 512, LBm, (size_t)i * 512, 512,
                             (const int*)flag);
        else
          hipLaunchKernelGGL(ln_kernel, dim3(Bc), dim3(256), 0, stream,
                             tA, 512, (void*)cat, (size_t)(mod * 512), 1024, 0,
                             Gm, (size_t)i * 512, LBm, (size_t)i * 512, 512,
                             (const int*)flag);
      }
    }

    gemm(cat, 0, 1024, 0, gate_w1, 0, 1024, gate_b1, 0, nullptr, 0,
         h1, 512, Bc, 512, 1024, 1);
    gemm(h1, 0, 512, 0, gate_w2, 0, 512, gate_b2, 0, nullptr, 0,
         h2, 256, Bc, 256, 512, 1);
    hipLaunchKernelGGL(gate3_kernel, dim3(Bc), dim3(256), 0, stream,
                       h2, gate_w3, gate_b3, gate_f,
                       d_out, (size_t)262144 + (size_t)row0 * 2,
                       (const int*)flag);
    hipLaunchKernelGGL(combine_kernel, dim3(Bc * 4), dim3(256), 0, stream,
                       cat, gate_f, xbuf);

    for (int i = 0; i < 3; ++i) {
      gemm(xbuf, 0, 1024, 0, in_proj_w, (size_t)i * 4194304, 1024,
           conv_b, (size_t)i * 2048, conv_w, (size_t)i * 8192,
           xc, 2048, Bc, 2048, 1024, 2);
      gemm(xbuf, 0, 1024, 0, in_proj_w,
           (size_t)i * 4194304 + (size_t)2048 * 1024, 1024,
           nullptr, 0, nullptr, 0, zs, 2048, Bc, 2048, 1024, 3);
      gemm(xc, 0, 2048, 0, x_proj_w, (size_t)i * 196608, 2048,
           nullptr, 0, nullptr, 0, dbc, 96, Bc, 96, 2048, 0);
      gemm(dbc, 0, 96, 0, dt_proj_w, (size_t)i * 131072, 64,
           nullptr, 0, nullptr, 0, du, 2048, Bc, 2048, 64, 0);
      hipLaunchKernelGGL(mamba_y_kernel, dim3(Bc), dim3(256), 0, stream,
                         du, dt_proj_b, (size_t)i * 2048, xc, zs, dbc,
                         D_param, (size_t)i * 2048, (const int*)flag);
      gemm(du, 0, 2048, 0, out_proj_w, (size_t)i * 2097152, 2048,
           nullptr, 0, nullptr, 0, mo, 1024, Bc, 1024, 2048, 0);
      hipLaunchKernelGGL(addln_kernel, dim3(Bc), dim3(256), 0, stream,
                         mo, xbuf, xbuf, mnorm_g, (size_t)i * 1024,
                         mnorm_b, (size_t)i * 1024, (const int*)flag);
    }

    gemm(xbuf, 0, 1024, 0, fc_w, 0, 1024, fc_b, 0, nullptr, 0,
         fcb, 256, Bc, 256, 1024, 0);
    hipLaunchKernelGGL(ln_kernel, dim3(Bc), dim3(256), 0, stream,
                       fcb, 256, d_out, (size_t)row0 * 256, 256, 1,
                       final_g, 0, final_b, 0, 256, (const int*)flag);
  }
}